// Round 4
// baseline (135.765 us; speedup 1.0000x reference)
//
#include <hip/hip_runtime.h>

// Fused CNN, single kernel (R4): prep_w2 eliminated — A-fragments are built
// in-register from raw fp32 w2 (72-contiguous-float runs per lane, 18 float4
// L2-cached loads, RNE-converted to bf16). Stage-1 image reads vectorized to
// ds_read_b128. conv2 = bf16 MFMA 16x16x32, M=64, N=100(pad 112), K=576,
// K-order (ky,kx,cin). One block per image, 256 threads, LDS 29.7 KB.

typedef __attribute__((ext_vector_type(8))) short short8;   // 8 x bf16 (4 VGPRs)
typedef __attribute__((ext_vector_type(4))) float f32x4;

__device__ inline short f2bf(float f) {   // fp32 -> bf16, round-to-nearest-even
    union { float f; unsigned u; } v; v.f = f;
    unsigned r = (v.u + 0x7FFFu + ((v.u >> 16) & 1u)) >> 16;
    return (short)r;
}

__global__ __launch_bounds__(256) void convnet_fused(
    const float* __restrict__ x,   // [B,1,28,28]
    const float* __restrict__ w1,  // [64,1,3,3]
    const float* __restrict__ b1,  // [64]
    const float* __restrict__ w2,  // [64,64,3,3] raw fp32
    const float* __restrict__ b2,  // [64]
    const float* __restrict__ w3,  // [10,64,4,4]
    const float* __restrict__ b3,  // [10]
    float* __restrict__ out)       // [B,10]
{
    // Overlay plan (floats):
    //   [0..5184)    h1t bf16 [144 pos][72 cin-stride] -> later conv2buf fp32 [64][100] ([0..6400))
    //   [5184..5968) img 28x28                         -> (absorbed by conv2buf)
    //   [6400..7424) h2t fp32 [16 pos][64 cin]
    //   [0..160)     stage-3 partials (conv2buf dead by then)
    __shared__ float lds_f[7424];                // 29696 B
    short* h1t  = (short*)lds_f;
    float* img  = lds_f + 5184;
    float* cbuf = lds_f;                         // conv2buf fp32 [64][100]
    float* h2t  = lds_f + 6400;
    float* prt  = lds_f;

    const int n_img = blockIdx.x;
    const int t = threadIdx.x;
    const int c = t >> 2;        // 0..63
    const int q = t & 3;         // quadrant

    // ---- load input image ----
    const float* img_g = x + (size_t)n_img * 784;
    for (int i = t; i < 784; i += 256) img[i] = img_g[i];
    __syncthreads();

    // ---- stage 1: conv1 + pool 3x3 s2 + relu -> h1t[pos][c] (bf16), each conv once ----
    {
        const int oy = (q >> 1) * 6, ox = (q & 1) * 6;   // pooled quadrant origin
        const int iy0 = 2 * oy, ix0 = 2 * ox;            // input region origin
        float w[9];
        #pragma unroll
        for (int k = 0; k < 9; ++k) w[k] = w1[c * 9 + k];
        const float bias = b1[c];

        float rows[3][16];                               // ring of 3 input rows (b128 loads)
        {
            const float* s0 = img + iy0 * 28 + ix0;
            const float* s1 = img + (iy0 + 1) * 28 + ix0;
            #pragma unroll
            for (int m = 0; m < 4; ++m) {
                *(float4*)(rows[0] + 4 * m) = *(const float4*)(s0 + 4 * m);
                *(float4*)(rows[1] + 4 * m) = *(const float4*)(s1 + 4 * m);
            }
        }
        float cm[3][6];                                  // colmax ring (3 conv rows)

        #pragma unroll
        for (int r = 0; r < 13; ++r) {                   // conv rows, computed once
            {
                const float* s2 = img + (iy0 + r + 2) * 28 + ix0;
                float* dst = rows[(r + 2) % 3];
                #pragma unroll
                for (int m = 0; m < 4; ++m)
                    *(float4*)(dst + 4 * m) = *(const float4*)(s2 + 4 * m);
            }
            const float* r0 = rows[r % 3];
            const float* r1 = rows[(r + 1) % 3];
            const float* r2 = rows[(r + 2) % 3];
            #pragma unroll
            for (int px = 0; px < 6; ++px) cm[r % 3][px] = -1e30f;
            #pragma unroll
            for (int xx = 0; xx < 13; ++xx) {
                float a = bias;
                #pragma unroll
                for (int j = 0; j < 3; ++j) {
                    a += r0[xx + j] * w[j];
                    a += r1[xx + j] * w[3 + j];
                    a += r2[xx + j] * w[6 + j];
                }
                if ((xx & 1) == 0) {
                    if (xx >= 2 && xx <= 12) cm[r % 3][xx / 2 - 1] = fmaxf(cm[r % 3][xx / 2 - 1], a);
                    if (xx <= 10)            cm[r % 3][xx / 2]     = fmaxf(cm[r % 3][xx / 2], a);
                } else {
                    cm[r % 3][xx / 2] = fmaxf(cm[r % 3][xx / 2], a);
                }
            }
            if (r >= 2 && (r & 1) == 0) {                // pooled row py = r/2 - 1 complete
                const int py = r / 2 - 1;
                #pragma unroll
                for (int px = 0; px < 6; ++px) {
                    float m = fmaxf(fmaxf(cm[0][px], cm[1][px]), cm[2][px]);
                    h1t[((oy + py) * 12 + ox + px) * 72 + c] = f2bf(fmaxf(m, 0.0f));
                }
            }
        }
    }
    __syncthreads();

    // ---- stage 2: conv2 as MFMA GEMM; A built in-register from raw w2 ----
    const int wv = t >> 6, lane = t & 63;
    const int quad = lane >> 4, mrow = lane & 15;
    {
        int base_el[7];
        #pragma unroll
        for (int nt = 0; nt < 7; ++nt) {
            int n = nt * 16 + mrow; if (n > 99) n = 99;   // clamp pad cols (discarded)
            int y = n / 10, xx = n - y * 10;
            base_el[nt] = (y * 12 + xx) * 72;
        }
        f32x4 acc[7];
        #pragma unroll
        for (int nt = 0; nt < 7; ++nt) acc[nt] = (f32x4){0.f, 0.f, 0.f, 0.f};

        const int cout = wv * 16 + mrow;
        #pragma unroll
        for (int h = 0; h < 2; ++h) {
            // A-frags for K-half h: w2[cout, c0..c0+8, s=0..8] = 72 contiguous floats.
            // frag af[s][j] = run[j*9 + s], RNE bf16.
            const int c0 = h * 32 + quad * 8;
            const float* runp = w2 + cout * 576 + c0 * 9;
            short8 af[9];
            #pragma unroll
            for (int m = 0; m < 18; ++m) {
                const float4 v = *(const float4*)(runp + 4 * m);
                const int i0 = 4 * m;
                af[(i0 + 0) % 9][(i0 + 0) / 9] = f2bf(v.x);
                af[(i0 + 1) % 9][(i0 + 1) / 9] = f2bf(v.y);
                af[(i0 + 2) % 9][(i0 + 2) / 9] = f2bf(v.z);
                af[(i0 + 3) % 9][(i0 + 3) / 9] = f2bf(v.w);
            }
            #pragma unroll
            for (int s = 0; s < 9; ++s) {
                const int ky = s / 3, kx = s - ky * 3;
                const int boff = (ky * 12 + kx) * 72 + h * 32 + quad * 8;
                #pragma unroll
                for (int nt = 0; nt < 7; ++nt) {
                    const short8 b = *(const short8*)(h1t + base_el[nt] + boff);
                    acc[nt] = __builtin_amdgcn_mfma_f32_16x16x32_bf16(af[s], b, acc[nt], 0, 0, 0);
                }
            }
        }
        __syncthreads();   // all h1t + img reads done; overlay region reusable
        // epilogue: D[row=quad*4+r][col=mrow] -> cbuf[cout'][pos] + bias
        #pragma unroll
        for (int nt = 0; nt < 7; ++nt) {
            const int n = nt * 16 + mrow;
            if (n < 100) {
                #pragma unroll
                for (int r = 0; r < 4; ++r) {
                    const int co = wv * 16 + quad * 4 + r;
                    cbuf[co * 100 + n] = acc[nt][r] + b2[co];
                }
            }
        }
    }
    __syncthreads();

    // ---- stage 2b: pool 3x3 s2 + relu -> h2t[pos][cin] fp32 ----
    {
        const float* cb = cbuf + c * 100;
        #pragma unroll
        for (int k = 0; k < 4; ++k) {
            const int pos = q * 4 + k;
            const int py = pos >> 2, px = pos & 3;
            float m = -1e30f;
            #pragma unroll
            for (int a = 0; a < 3; ++a)
                #pragma unroll
                for (int b = 0; b < 3; ++b)
                    m = fmaxf(m, cb[(2 * py + a) * 10 + (2 * px + b)]);
            h2t[pos * 64 + c] = fmaxf(m, 0.0f);
        }
    }
    __syncthreads();

    // ---- stage 3: conv3 4x4 -> out[n][10] ----
    if (t < 160) {
        const int o = t >> 4, l = t & 15;
        const float* w3o = w3 + o * 1024;
        float s = 0.0f;
        #pragma unroll
        for (int cc = 0; cc < 4; ++cc) {
            const int cin = l * 4 + cc;
            const float4 wv4a = *(const float4*)(w3o + cin * 16);
            const float4 wv4b = *(const float4*)(w3o + cin * 16 + 4);
            const float4 wv4c = *(const float4*)(w3o + cin * 16 + 8);
            const float4 wv4d = *(const float4*)(w3o + cin * 16 + 12);
            const float* hh = h2t + cin;
            s += hh[0*64] * wv4a.x + hh[1*64] * wv4a.y + hh[2*64] * wv4a.z + hh[3*64] * wv4a.w;
            s += hh[4*64] * wv4b.x + hh[5*64] * wv4b.y + hh[6*64] * wv4b.z + hh[7*64] * wv4b.w;
            s += hh[8*64] * wv4c.x + hh[9*64] * wv4c.y + hh[10*64] * wv4c.z + hh[11*64] * wv4c.w;
            s += hh[12*64] * wv4d.x + hh[13*64] * wv4d.y + hh[14*64] * wv4d.z + hh[15*64] * wv4d.w;
        }
        prt[t] = s;   // cbuf dead (pool reads barriered above)
    }
    __syncthreads();
    if (t < 10) {
        float s = b3[t];
        #pragma unroll
        for (int l = 0; l < 16; ++l) s += prt[t * 16 + l];
        out[(size_t)n_img * 10 + t] = s;
    }
}

extern "C" void kernel_launch(void* const* d_in, const int* in_sizes, int n_in,
                              void* d_out, int out_size, void* d_ws, size_t ws_size,
                              hipStream_t stream) {
    const float* x  = (const float*)d_in[0];
    const float* w1 = (const float*)d_in[1];
    const float* b1 = (const float*)d_in[2];
    const float* w2 = (const float*)d_in[3];
    const float* b2 = (const float*)d_in[4];
    const float* w3 = (const float*)d_in[5];
    const float* b3 = (const float*)d_in[6];
    float* out = (float*)d_out;

    const int B = in_sizes[0] / 784;      // 2048
    convnet_fused<<<B, 256, 0, stream>>>(x, w1, b1, w2, b2, w3, b3, out);
}

// Round 5
// 130.477 us; speedup vs baseline: 1.0405x; 1.0405x over previous
//
#include <hip/hip_runtime.h>

// R5: LDS-pipe attack. Two kernels (prep_w2 restored — R4 proved in-register A-build
// from raw w2 is TA-serialization death). Main kernel changes vs R3:
//  - stage 1 reads image rows straight from global (L1 broadcast), zero LDS reads
//  - conv2 uses mfma_f32_32x32x16_bf16: 2 (M,N) 32-tiles/wave, 36 K-steps,
//    72 b128 B-reads/wave (was 126)
//  - cbuf stride 101 (conflict-free pool reads), stage-3 b128 reads along cin
// LDS 29952 B -> 5 blocks/CU.

typedef __attribute__((ext_vector_type(8))) short short8;    // 8 x bf16
typedef __attribute__((ext_vector_type(16))) float f32x16;   // 32x32 accumulator

__device__ inline short f2bf(float f) {   // fp32 -> bf16, round-to-nearest-even
    union { float f; unsigned u; } v; v.f = f;
    unsigned r = (v.u + 0x7FFFu + ((v.u >> 16) & 1u)) >> 16;
    return (short)r;
}

// w2r[s][cout][cin] (bf16), s = ky*3+kx: MFMA A-fragments contiguous in cin.
__global__ __launch_bounds__(256) void prep_w2(const float* __restrict__ w2,
                                               short* __restrict__ w2r) {
    int i = blockIdx.x * 256 + threadIdx.x;      // 9*64*64 = 36864
    if (i >= 36864) return;
    int s = i >> 12, cout = (i >> 6) & 63, cin = i & 63;
    w2r[i] = f2bf(w2[cout * 576 + cin * 9 + s]);
}

__global__ __launch_bounds__(256) void convnet_fused(
    const float* __restrict__ x,   // [B,1,28,28]
    const float* __restrict__ w1,  // [64,1,3,3]
    const float* __restrict__ b1,  // [64]
    const short* __restrict__ w2r, // [9][64][64] bf16
    const float* __restrict__ b2,  // [64]
    const float* __restrict__ w3,  // [10,64,4,4]
    const float* __restrict__ b3,  // [10]
    float* __restrict__ out)       // [B,10]
{
    // Overlays (floats):
    //   [0..5184)    h1t bf16 [144 pos][72]   -> cbuf fp32 [64][101] = [0..6464)
    //   [6464..7488) h2t fp32 [16 pos][64 cin]
    //   [0..160)     stage-3 partials (cbuf dead)
    __shared__ float lds_f[7488];                // 29952 B
    short* h1t  = (short*)lds_f;
    float* cbuf = lds_f;
    float* h2t  = lds_f + 6464;
    float* prt  = lds_f;

    const int n_img = blockIdx.x;
    const int t = threadIdx.x;
    const int c = t >> 2;        // 0..63
    const int q = t & 3;         // quadrant

    const float* img_g = x + (size_t)n_img * 784;

    // ---- stage 1: conv1 + pool + relu -> h1t[pos][c] bf16; image via global L1 ----
    {
        const int oy = (q >> 1) * 6, ox = (q & 1) * 6;
        const int iy0 = 2 * oy, ix0 = 2 * ox;            // 16B-aligned (28y+{0,12})
        float w[9];
        #pragma unroll
        for (int k = 0; k < 9; ++k) w[k] = w1[c * 9 + k];
        const float bias = b1[c];

        float rows[3][16];
        {
            const float* s0 = img_g + iy0 * 28 + ix0;
            const float* s1 = img_g + (iy0 + 1) * 28 + ix0;
            #pragma unroll
            for (int m = 0; m < 4; ++m) {
                *(float4*)(rows[0] + 4 * m) = *(const float4*)(s0 + 4 * m);
                *(float4*)(rows[1] + 4 * m) = *(const float4*)(s1 + 4 * m);
            }
        }
        float cm[3][6];
        #pragma unroll
        for (int r = 0; r < 13; ++r) {
            {
                const float* s2 = img_g + (iy0 + r + 2) * 28 + ix0;
                float* dst = rows[(r + 2) % 3];
                #pragma unroll
                for (int m = 0; m < 4; ++m)
                    *(float4*)(dst + 4 * m) = *(const float4*)(s2 + 4 * m);
            }
            const float* r0 = rows[r % 3];
            const float* r1 = rows[(r + 1) % 3];
            const float* r2 = rows[(r + 2) % 3];
            #pragma unroll
            for (int px = 0; px < 6; ++px) cm[r % 3][px] = -1e30f;
            #pragma unroll
            for (int xx = 0; xx < 13; ++xx) {
                float a = bias;
                #pragma unroll
                for (int j = 0; j < 3; ++j) {
                    a += r0[xx + j] * w[j];
                    a += r1[xx + j] * w[3 + j];
                    a += r2[xx + j] * w[6 + j];
                }
                if ((xx & 1) == 0) {
                    if (xx >= 2 && xx <= 12) cm[r % 3][xx / 2 - 1] = fmaxf(cm[r % 3][xx / 2 - 1], a);
                    if (xx <= 10)            cm[r % 3][xx / 2]     = fmaxf(cm[r % 3][xx / 2], a);
                } else {
                    cm[r % 3][xx / 2] = fmaxf(cm[r % 3][xx / 2], a);
                }
            }
            if (r >= 2 && (r & 1) == 0) {
                const int py = r / 2 - 1;
                #pragma unroll
                for (int px = 0; px < 6; ++px) {
                    float m = fmaxf(fmaxf(cm[0][px], cm[1][px]), cm[2][px]);
                    h1t[((oy + py) * 12 + ox + px) * 72 + c] = f2bf(fmaxf(m, 0.0f));
                }
            }
        }
    }
    __syncthreads();

    // ---- stage 2: conv2 via mfma_32x32x16. M=64 (2 tiles), N=100 pad 128 (4 tiles),
    //      K=576 = 36 steps of 16. Wave wv: mtile = wv&1, ntiles {2*(wv>>1), +1}. ----
    const int wv = t >> 6, lane = t & 63;
    const int mtile = wv & 1, npair = wv >> 1;
    const int col32 = lane & 31, khalf = lane >> 5;
    {
        int base_el[2];
        #pragma unroll
        for (int nt2 = 0; nt2 < 2; ++nt2) {
            int n = (npair * 2 + nt2) * 32 + col32;
            if (n > 99) n = 99;                      // pad cols read valid junk, discarded
            int y = n / 10, xx = n - y * 10;
            base_el[nt2] = (y * 12 + xx) * 72;
        }
        f32x16 acc[2];
        #pragma unroll
        for (int nt2 = 0; nt2 < 2; ++nt2)
            #pragma unroll
            for (int r = 0; r < 16; ++r) acc[nt2][r] = 0.0f;

        #pragma unroll
        for (int step = 0; step < 36; ++step) {
            const int s = step >> 2;
            const int cinb = (step & 3) * 16 + khalf * 8;
            const short8 a = *(const short8*)(w2r + s * 4096 + (mtile * 32 + col32) * 64 + cinb);
            const int ky = s / 3, kx = s - ky * 3;
            const int toff = (ky * 12 + kx) * 72 + cinb;
            #pragma unroll
            for (int nt2 = 0; nt2 < 2; ++nt2) {
                const short8 b = *(const short8*)(h1t + base_el[nt2] + toff);
                acc[nt2] = __builtin_amdgcn_mfma_f32_32x32x16_bf16(a, b, acc[nt2], 0, 0, 0);
            }
        }
        __syncthreads();   // all h1t reads done; overlay region reusable
        // C/D: col = lane&31, row = (reg&3) + 8*(reg>>2) + 4*khalf   [m74/m101]
        #pragma unroll
        for (int nt2 = 0; nt2 < 2; ++nt2) {
            const int n = (npair * 2 + nt2) * 32 + col32;
            if (n < 100) {
                #pragma unroll
                for (int reg = 0; reg < 16; ++reg) {
                    const int row = (reg & 3) + 8 * (reg >> 2) + 4 * khalf;
                    const int cout = mtile * 32 + row;
                    cbuf[cout * 101 + n] = acc[nt2][reg] + b2[cout];
                }
            }
        }
    }
    __syncthreads();

    // ---- stage 2b: pool 3x3 s2 + relu -> h2t[pos][cin]; stride-101 reads conflict-free ----
    {
        const float* cb = cbuf + c * 101;
        #pragma unroll
        for (int k = 0; k < 4; ++k) {
            const int pos = q * 4 + k;
            const int py = pos >> 2, px = pos & 3;
            float m = -1e30f;
            #pragma unroll
            for (int a = 0; a < 3; ++a)
                #pragma unroll
                for (int b = 0; b < 3; ++b)
                    m = fmaxf(m, cb[(2 * py + a) * 10 + (2 * px + b)]);
            h2t[pos * 64 + c] = fmaxf(m, 0.0f);
        }
    }
    __syncthreads();

    // ---- stage 3: conv3 4x4. Thread (o, g): cins 4g..4g+3, all 16 pos.
    //      h2t reads are b128 along cin (banks 4g..4g+3, 2-way = free). ----
    if (t < 160) {
        const int o = t >> 4, g = t & 15;
        const float* w3o = w3 + o * 1024 + g * 64;   // [4 cc][16 pos] contiguous
        float wr[4][16];
        #pragma unroll
        for (int cc = 0; cc < 4; ++cc)
            #pragma unroll
            for (int m = 0; m < 4; ++m)
                *(float4*)(wr[cc] + 4 * m) = *(const float4*)(w3o + cc * 16 + 4 * m);
        float s = 0.0f;
        #pragma unroll
        for (int pos = 0; pos < 16; ++pos) {
            const float4 hv = *(const float4*)(h2t + pos * 64 + g * 4);
            s += hv.x * wr[0][pos] + hv.y * wr[1][pos] + hv.z * wr[2][pos] + hv.w * wr[3][pos];
        }
        prt[t] = s;   // overlays cbuf start; pool reads barriered above
    }
    __syncthreads();
    if (t < 10) {
        float s = b3[t];
        #pragma unroll
        for (int g = 0; g < 16; ++g) s += prt[t * 16 + g];
        out[(size_t)n_img * 10 + t] = s;
    }
}

extern "C" void kernel_launch(void* const* d_in, const int* in_sizes, int n_in,
                              void* d_out, int out_size, void* d_ws, size_t ws_size,
                              hipStream_t stream) {
    const float* x  = (const float*)d_in[0];
    const float* w1 = (const float*)d_in[1];
    const float* b1 = (const float*)d_in[2];
    const float* w2 = (const float*)d_in[3];
    const float* b2 = (const float*)d_in[4];
    const float* w3 = (const float*)d_in[5];
    const float* b3 = (const float*)d_in[6];
    float* out = (float*)d_out;
    short* w2r = (short*)d_ws;            // 36864 bf16 = 73728 B

    const int B = in_sizes[0] / 784;      // 2048
    prep_w2<<<144, 256, 0, stream>>>(w2, w2r);
    convnet_fused<<<B, 256, 0, stream>>>(x, w1, b1, w2r, b2, w3, b3, out);
}

// Round 6
// 112.025 us; speedup vs baseline: 1.2119x; 1.1647x over previous
//
#include <hip/hip_runtime.h>

// R6 = R3 base + proven fixes only:
//  - R3: LDS image + 16x16x32 MFMA + prep_w2 (R4/R5 proved global-img and 32x32 regress)
//  - R4: stage-1 image rows via ds_read_b128 (4 bcast addrs/inst, ~free on LDS pipe)
//  - R5: cbuf stride 101 (conflict-free pool), stage-3 b128-along-cin
// LDS 29952 B -> 5 blocks/CU.

typedef __attribute__((ext_vector_type(8))) short short8;   // 8 x bf16 (4 VGPRs)
typedef __attribute__((ext_vector_type(4))) float f32x4;

__device__ inline short f2bf(float f) {   // fp32 -> bf16, round-to-nearest-even
    union { float f; unsigned u; } v; v.f = f;
    unsigned r = (v.u + 0x7FFFu + ((v.u >> 16) & 1u)) >> 16;
    return (short)r;
}

// w2r[s][cout][cin] (bf16), s = ky*3+kx: MFMA A-fragments contiguous in cin.
__global__ __launch_bounds__(256) void prep_w2(const float* __restrict__ w2,
                                               short* __restrict__ w2r) {
    int i = blockIdx.x * 256 + threadIdx.x;      // 9*64*64 = 36864
    if (i >= 36864) return;
    int s = i >> 12, cout = (i >> 6) & 63, cin = i & 63;
    w2r[i] = f2bf(w2[cout * 576 + cin * 9 + s]);
}

__global__ __launch_bounds__(256) void convnet_fused(
    const float* __restrict__ x,   // [B,1,28,28]
    const float* __restrict__ w1,  // [64,1,3,3]
    const float* __restrict__ b1,  // [64]
    const short* __restrict__ w2r, // [9][64][64] bf16
    const float* __restrict__ b2,  // [64]
    const float* __restrict__ w3,  // [10,64,4,4]
    const float* __restrict__ b3,  // [10]
    float* __restrict__ out)       // [B,10]
{
    // Overlays (floats):
    //   [0..5184)    h1t bf16 [144 pos][72]    }-> cbuf fp32 [64][101] = [0..6464)
    //   [5184..5968) img 28x28                 }   (h1t & img dead by cbuf write)
    //   [6464..7488) h2t fp32 [16 pos][64 cin]
    //   [0..160)     stage-3 partials (cbuf dead)
    __shared__ float lds_f[7488];                // 29952 B
    short* h1t  = (short*)lds_f;
    float* img  = lds_f + 5184;
    float* cbuf = lds_f;
    float* h2t  = lds_f + 6464;
    float* prt  = lds_f;

    const int n_img = blockIdx.x;
    const int t = threadIdx.x;
    const int c = t >> 2;        // 0..63
    const int q = t & 3;         // quadrant

    // ---- load input image into LDS ----
    const float* img_g = x + (size_t)n_img * 784;
    for (int i = t; i < 784; i += 256) img[i] = img_g[i];
    __syncthreads();

    // ---- stage 1: conv1 + pool 3x3 s2 + relu -> h1t[pos][c] bf16, each conv once ----
    {
        const int oy = (q >> 1) * 6, ox = (q & 1) * 6;   // pooled quadrant origin
        const int iy0 = 2 * oy, ix0 = 2 * ox;            // 16B-aligned (28y + {0,12})
        float w[9];
        #pragma unroll
        for (int k = 0; k < 9; ++k) w[k] = w1[c * 9 + k];
        const float bias = b1[c];

        float rows[3][16];                               // ring of 3 input rows (b128)
        {
            const float* s0 = img + iy0 * 28 + ix0;
            const float* s1 = img + (iy0 + 1) * 28 + ix0;
            #pragma unroll
            for (int m = 0; m < 4; ++m) {
                *(float4*)(rows[0] + 4 * m) = *(const float4*)(s0 + 4 * m);
                *(float4*)(rows[1] + 4 * m) = *(const float4*)(s1 + 4 * m);
            }
        }
        float cm[3][6];                                  // colmax ring (3 conv rows)

        #pragma unroll
        for (int r = 0; r < 13; ++r) {                   // conv rows, computed once
            {
                const float* s2 = img + (iy0 + r + 2) * 28 + ix0;
                float* dst = rows[(r + 2) % 3];
                #pragma unroll
                for (int m = 0; m < 4; ++m)
                    *(float4*)(dst + 4 * m) = *(const float4*)(s2 + 4 * m);
            }
            const float* r0 = rows[r % 3];
            const float* r1 = rows[(r + 1) % 3];
            const float* r2 = rows[(r + 2) % 3];
            #pragma unroll
            for (int px = 0; px < 6; ++px) cm[r % 3][px] = -1e30f;
            #pragma unroll
            for (int xx = 0; xx < 13; ++xx) {
                float a = bias;
                #pragma unroll
                for (int j = 0; j < 3; ++j) {
                    a += r0[xx + j] * w[j];
                    a += r1[xx + j] * w[3 + j];
                    a += r2[xx + j] * w[6 + j];
                }
                if ((xx & 1) == 0) {
                    if (xx >= 2 && xx <= 12) cm[r % 3][xx / 2 - 1] = fmaxf(cm[r % 3][xx / 2 - 1], a);
                    if (xx <= 10)            cm[r % 3][xx / 2]     = fmaxf(cm[r % 3][xx / 2], a);
                } else {
                    cm[r % 3][xx / 2] = fmaxf(cm[r % 3][xx / 2], a);
                }
            }
            if (r >= 2 && (r & 1) == 0) {                // pooled row py = r/2 - 1 done
                const int py = r / 2 - 1;
                #pragma unroll
                for (int px = 0; px < 6; ++px) {
                    float m = fmaxf(fmaxf(cm[0][px], cm[1][px]), cm[2][px]);
                    h1t[((oy + py) * 12 + ox + px) * 72 + c] = f2bf(fmaxf(m, 0.0f));
                }
            }
        }
    }
    __syncthreads();

    // ---- stage 2: conv2 as MFMA GEMM (16x16x32), M=64, N=100 pad 112, K=576 ----
    const int wv = t >> 6, lane = t & 63;
    const int quad = lane >> 4, mrow = lane & 15;
    {
        int base_el[7];
        #pragma unroll
        for (int nt = 0; nt < 7; ++nt) {
            int n = nt * 16 + mrow; if (n > 99) n = 99;   // pad cols: valid junk, discarded
            int y = n / 10, xx = n - y * 10;
            base_el[nt] = (y * 12 + xx) * 72;
        }
        f32x4 acc[7];
        #pragma unroll
        for (int nt = 0; nt < 7; ++nt) acc[nt] = (f32x4){0.f, 0.f, 0.f, 0.f};

        #pragma unroll
        for (int ks = 0; ks < 18; ++ks) {
            const int s = ks >> 1, h = ks & 1;
            const int ky = s / 3, kx = s - ky * 3;
            const short8 a = *(const short8*)(w2r + s * 4096 + (wv * 16 + mrow) * 64
                                              + h * 32 + quad * 8);
            #pragma unroll
            for (int nt = 0; nt < 7; ++nt) {
                const short8 b = *(const short8*)(h1t + base_el[nt]
                                                  + (ky * 12 + kx) * 72 + h * 32 + quad * 8);
                acc[nt] = __builtin_amdgcn_mfma_f32_16x16x32_bf16(a, b, acc[nt], 0, 0, 0);
            }
        }
        __syncthreads();   // all h1t + img reads done; overlay region reusable
        // epilogue: D[row=quad*4+r][col=mrow] -> cbuf[cout][n] + bias, stride 101
        #pragma unroll
        for (int nt = 0; nt < 7; ++nt) {
            const int n = nt * 16 + mrow;
            if (n < 100) {
                #pragma unroll
                for (int r = 0; r < 4; ++r) {
                    const int co = wv * 16 + quad * 4 + r;
                    cbuf[co * 101 + n] = acc[nt][r] + b2[co];
                }
            }
        }
    }
    __syncthreads();

    // ---- stage 2b: pool 3x3 s2 + relu -> h2t[pos][cin]; stride 101 => no conflicts ----
    {
        const float* cb = cbuf + c * 101;
        #pragma unroll
        for (int k = 0; k < 4; ++k) {
            const int pos = q * 4 + k;
            const int py = pos >> 2, px = pos & 3;
            float m = -1e30f;
            #pragma unroll
            for (int a = 0; a < 3; ++a)
                #pragma unroll
                for (int b = 0; b < 3; ++b)
                    m = fmaxf(m, cb[(2 * py + a) * 10 + (2 * px + b)]);
            h2t[pos * 64 + c] = fmaxf(m, 0.0f);
        }
    }
    __syncthreads();

    // ---- stage 3: conv3 4x4. Thread (o,g): cins 4g..4g+3 via b128 (2-way = free) ----
    if (t < 160) {
        const int o = t >> 4, g = t & 15;
        const float* w3o = w3 + o * 1024 + g * 64;   // [4 cc][16 pos] contiguous
        float wr[4][16];
        #pragma unroll
        for (int cc = 0; cc < 4; ++cc)
            #pragma unroll
            for (int m = 0; m < 4; ++m)
                *(float4*)(wr[cc] + 4 * m) = *(const float4*)(w3o + cc * 16 + 4 * m);
        float s = 0.0f;
        #pragma unroll
        for (int pos = 0; pos < 16; ++pos) {
            const float4 hv = *(const float4*)(h2t + pos * 64 + g * 4);
            s += hv.x * wr[0][pos] + hv.y * wr[1][pos] + hv.z * wr[2][pos] + hv.w * wr[3][pos];
        }
        prt[t] = s;   // cbuf dead (pool reads barriered above)
    }
    __syncthreads();
    if (t < 10) {
        float s = b3[t];
        #pragma unroll
        for (int g = 0; g < 16; ++g) s += prt[t * 16 + g];
        out[(size_t)n_img * 10 + t] = s;
    }
}

extern "C" void kernel_launch(void* const* d_in, const int* in_sizes, int n_in,
                              void* d_out, int out_size, void* d_ws, size_t ws_size,
                              hipStream_t stream) {
    const float* x  = (const float*)d_in[0];
    const float* w1 = (const float*)d_in[1];
    const float* b1 = (const float*)d_in[2];
    const float* w2 = (const float*)d_in[3];
    const float* b2 = (const float*)d_in[4];
    const float* w3 = (const float*)d_in[5];
    const float* b3 = (const float*)d_in[6];
    float* out = (float*)d_out;
    short* w2r = (short*)d_ws;            // 36864 bf16 = 73728 B

    const int B = in_sizes[0] / 784;      // 2048
    prep_w2<<<144, 256, 0, stream>>>(w2, w2r);
    convnet_fused<<<B, 256, 0, stream>>>(x, w1, b1, w2r, b2, w3, b3, out);
}